// Round 4
// baseline (2218.157 us; speedup 1.0000x reference)
//
#include <hip/hip_runtime.h>
#include <stdint.h>

// ---------------------------------------------------------------------------
// UpBlock: 5 chained sparse convs (gather-GEMM), bf16 MFMA, no LDS.
// R4: R1 shape (1 wave/block, m=64 n=64, 2x2 acc) + template K + all-index
// register prefetch + L2-SEGMENTED gathers for the CIN=64,K=27 layers:
// loop g over 16384-row (2 MB) table slices; gather only lanes whose index
// is in slice g (exec-masked), MFMA every pass (zeros elsewhere), acc stays
// in registers. Keeps the live random-gather footprint L2-resident.
// mfma_f32_32x32x16_bf16:
//   A[m=lane&31][k=(lane>>5)*8+j], B[k=(lane>>5)*8+j][n=lane&31]
//   C/D: col=lane&31, row=(reg&3)+8*(reg>>2)+4*(lane>>5)
// ---------------------------------------------------------------------------

typedef __bf16 bf16x8 __attribute__((ext_vector_type(8)));
typedef float f32x16 __attribute__((ext_vector_type(16)));

__device__ __forceinline__ uint16_t f2bf(float f) {
    uint32_t u = __builtin_bit_cast(uint32_t, f);
    u = (u + 0x7fffu + ((u >> 16) & 1u)) >> 16;   // round-to-nearest-even
    return (uint16_t)u;
}

__device__ __forceinline__ bf16x8 ldb8(const uint16_t* p) {
    return __builtin_bit_cast(bf16x8, *reinterpret_cast<const uint4*>(p));
}

// --- convert x_feats (f32) -> bf16, 8 elems/thread --------------------------
__global__ void convert_x(const float* __restrict__ in, uint16_t* __restrict__ out, int n8) {
    int t = blockIdx.x * blockDim.x + threadIdx.x;
    if (t >= n8) return;
    const float4* p = reinterpret_cast<const float4*>(in) + 2 * (size_t)t;
    float4 f0 = p[0], f1 = p[1];
    uint32_t w0 = (uint32_t)f2bf(f0.x) | ((uint32_t)f2bf(f0.y) << 16);
    uint32_t w1 = (uint32_t)f2bf(f0.z) | ((uint32_t)f2bf(f0.w) << 16);
    uint32_t w2 = (uint32_t)f2bf(f1.x) | ((uint32_t)f2bf(f1.y) << 16);
    uint32_t w3 = (uint32_t)f2bf(f1.z) | ((uint32_t)f2bf(f1.w) << 16);
    uint4 v; v.x = w0; v.y = w1; v.z = w2; v.w = w3;
    *reinterpret_cast<uint4*>(out + 8 * (size_t)t) = v;
}

// --- pack weights into MFMA B-fragment order + BN scale/shift ---------------
// dst element [(((k*S + s)*2 + nt)*64 + lane)*8 + j] = bf16(W[k][ci][c])
//   ci = s*16 + (lane>>5)*8 + j,  c = nt*32 + (lane&31),  S = CIN/16
__global__ void pack_weights(const float* __restrict__ w1, const float* __restrict__ wt,
                             const float* __restrict__ w2, const float* __restrict__ w3,
                             const float* __restrict__ w4, const float* __restrict__ bn,
                             uint16_t* __restrict__ p1, uint16_t* __restrict__ pt,
                             uint16_t* __restrict__ p2, uint16_t* __restrict__ p3,
                             uint16_t* __restrict__ p4, float* __restrict__ bnps) {
    int w = blockIdx.y;
    int t = blockIdx.x * blockDim.x + threadIdx.x;
    if (w == 5) {  // BN scale/shift precompute: bnps[l][0][c]=scale, [l][1][c]=shift
        if (t < 256) {
            int l = t >> 6, c = t & 63;
            float g = bn[(l * 4 + 0) * 64 + c];
            float b = bn[(l * 4 + 1) * 64 + c];
            float m = bn[(l * 4 + 2) * 64 + c];
            float v = bn[(l * 4 + 3) * 64 + c];
            float sc = g * rsqrtf(v + 1e-5f);
            bnps[(l * 2 + 0) * 64 + c] = sc;
            bnps[(l * 2 + 1) * 64 + c] = b - m * sc;
        }
        return;
    }
    const float* src; uint16_t* dst; int K, CIN;
    switch (w) {
        case 0:  src = w1; dst = p1; K = 27; CIN = 128; break;
        case 1:  src = wt; dst = pt; K = 27; CIN = 64;  break;
        case 2:  src = w2; dst = p2; K = 9;  CIN = 64;  break;
        case 3:  src = w3; dst = p3; K = 9;  CIN = 64;  break;
        default: src = w4; dst = p4; K = 27; CIN = 64;  break;
    }
    int S = CIN / 16;
    int F = K * S * 2 * 64;
    if (t >= F) return;
    int lane = t & 63;
    int r = t >> 6;
    int nt = r & 1; r >>= 1;
    int s = r % S;
    int k = r / S;
    int c = nt * 32 + (lane & 31);
    int cib = s * 16 + (lane >> 5) * 8;
    #pragma unroll
    for (int j = 0; j < 8; ++j)
        dst[(size_t)t * 8 + j] = f2bf(src[((size_t)k * CIN + cib + j) * 64 + c]);
}

// --- one sparse-conv layer ---------------------------------------------------
// 1 wave/block, m=64 (2 rows/lane-group), n=64, 2x2 MFMA accumulators.
// G>1: segment loop over (1<<LOG2R)-row table slices for L2 residency.
// MODE 0: BN+LeakyReLU -> bf16   MODE 1: +skip -> bf16   MODE 2: BN+LeakyReLU -> f32
template <int CIN, int K, int MODE, int G, int LOG2R>
__global__ __launch_bounds__(64)
void conv_layer(const uint16_t* __restrict__ feats,  // [N][CIN] bf16
                const uint16_t* __restrict__ wf,     // packed [K][CIN/16][2][64][8] bf16
                const int* __restrict__ nbr,         // [K][N]
                const int npts,
                const float* __restrict__ bnp,       // [2][64] scale/shift (or null)
                const float* __restrict__ skip,      // [N][64] f32 (or null)
                uint16_t* __restrict__ outb,
                float* __restrict__ outf) {
    constexpr int S = CIN / 16;
    const int lane = threadIdx.x;
    const int l31  = lane & 31;
    const int hi   = lane >> 5;          // which K-half of the fragment
    const int base = blockIdx.x * 64;
    const int g0   = min(base + l31, npts - 1);
    const int g1   = min(base + 32 + l31, npts - 1);

    // prefetch ALL tap indices into registers (coalesced; breaks idx->gather chain)
    int idx0[K], idx1[K];
    #pragma unroll
    for (int k = 0; k < K; ++k) {
        idx0[k] = nbr[(size_t)k * npts + g0];
        idx1[k] = nbr[(size_t)k * npts + g1];
    }

    f32x16 acc00 = {0,0,0,0,0,0,0,0,0,0,0,0,0,0,0,0};
    f32x16 acc01 = {0,0,0,0,0,0,0,0,0,0,0,0,0,0,0,0};
    f32x16 acc10 = {0,0,0,0,0,0,0,0,0,0,0,0,0,0,0,0};
    f32x16 acc11 = {0,0,0,0,0,0,0,0,0,0,0,0,0,0,0,0};

    uint4 z4; z4.x = 0; z4.y = 0; z4.z = 0; z4.w = 0;
    const bf16x8 zero = __builtin_bit_cast(bf16x8, z4);

    for (int g = 0; g < G; ++g) {      // uniform scalar segment loop
        const int lo = g << LOG2R;
        #pragma unroll
        for (int k = 0; k < K; ++k) {
            bf16x8 a0[S], a1[S];
            #pragma unroll
            for (int s = 0; s < S; ++s) { a0[s] = zero; a1[s] = zero; }
            bool in0 = true, in1 = true;
            if constexpr (G > 1) {
                in0 = (unsigned)(idx0[k] - lo) < (1u << LOG2R);
                in1 = (unsigned)(idx1[k] - lo) < (1u << LOG2R);
            }
            const uint16_t* a0p = feats + (size_t)idx0[k] * CIN + hi * 8;
            const uint16_t* a1p = feats + (size_t)idx1[k] * CIN + hi * 8;
            if (in0) {
                #pragma unroll
                for (int s = 0; s < S; ++s) a0[s] = ldb8(a0p + s * 16);
            }
            if (in1) {
                #pragma unroll
                for (int s = 0; s < S; ++s) a1[s] = ldb8(a1p + s * 16);
            }
            const uint16_t* bp = wf + (size_t)k * (S * 1024) + lane * 8;
            #pragma unroll
            for (int s = 0; s < S; ++s) {
                bf16x8 b0 = ldb8(bp + s * 1024);
                bf16x8 b1 = ldb8(bp + s * 1024 + 512);
                acc00 = __builtin_amdgcn_mfma_f32_32x32x16_bf16(a0[s], b0, acc00, 0, 0, 0);
                acc01 = __builtin_amdgcn_mfma_f32_32x32x16_bf16(a0[s], b1, acc01, 0, 0, 0);
                acc10 = __builtin_amdgcn_mfma_f32_32x32x16_bf16(a1[s], b0, acc10, 0, 0, 0);
                acc11 = __builtin_amdgcn_mfma_f32_32x32x16_bf16(a1[s], b1, acc11, 0, 0, 0);
            }
        }
    }

    const int c0 = l31, c1 = 32 + l31;
    float sc0 = 0.f, sh0 = 0.f, sc1 = 0.f, sh1 = 0.f;
    if (MODE != 1) {
        sc0 = bnp[c0]; sh0 = bnp[64 + c0];
        sc1 = bnp[c1]; sh1 = bnp[64 + c1];
    }
    #pragma unroll
    for (int reg = 0; reg < 16; ++reg) {
        const int row = (reg & 3) + 8 * (reg >> 2) + 4 * hi;
        const int gr0 = base + row;
        const int gr1 = base + 32 + row;
        float v00 = acc00[reg], v01 = acc01[reg];
        float v10 = acc10[reg], v11 = acc11[reg];
        if (MODE != 1) {
            v00 = v00 * sc0 + sh0; v00 = v00 >= 0.f ? v00 : 0.01f * v00;
            v01 = v01 * sc1 + sh1; v01 = v01 >= 0.f ? v01 : 0.01f * v01;
            v10 = v10 * sc0 + sh0; v10 = v10 >= 0.f ? v10 : 0.01f * v10;
            v11 = v11 * sc1 + sh1; v11 = v11 >= 0.f ? v11 : 0.01f * v11;
        }
        if (gr0 < npts) {
            if (MODE == 1) { v00 += skip[(size_t)gr0 * 64 + c0]; v01 += skip[(size_t)gr0 * 64 + c1]; }
            if (MODE == 2) {
                outf[(size_t)gr0 * 64 + c0] = v00; outf[(size_t)gr0 * 64 + c1] = v01;
            } else {
                outb[(size_t)gr0 * 64 + c0] = f2bf(v00); outb[(size_t)gr0 * 64 + c1] = f2bf(v01);
            }
        }
        if (gr1 < npts) {
            if (MODE == 1) { v10 += skip[(size_t)gr1 * 64 + c0]; v11 += skip[(size_t)gr1 * 64 + c1]; }
            if (MODE == 2) {
                outf[(size_t)gr1 * 64 + c0] = v10; outf[(size_t)gr1 * 64 + c1] = v11;
            } else {
                outb[(size_t)gr1 * 64 + c0] = f2bf(v10); outb[(size_t)gr1 * 64 + c1] = f2bf(v11);
            }
        }
    }
}

extern "C" void kernel_launch(void* const* d_in, const int* in_sizes, int n_in,
                              void* d_out, int out_size, void* d_ws, size_t ws_size,
                              hipStream_t stream) {
    const int N = in_sizes[0] / 128;
    const float* x    = (const float*)d_in[0];
    const float* skip = (const float*)d_in[1];
    const float* W1   = (const float*)d_in[2];
    const float* Wt   = (const float*)d_in[3];
    const float* W2   = (const float*)d_in[4];
    const float* W3   = (const float*)d_in[5];
    const float* W4   = (const float*)d_in[6];
    const float* bn   = (const float*)d_in[7];
    const int* nbr1   = (const int*)d_in[8];
    const int* nbrt   = (const int*)d_in[9];
    const int* nbr2   = (const int*)d_in[10];
    const int* nbr3   = (const int*)d_in[11];
    const int* nbr4   = (const int*)d_in[12];

    uint8_t* ws = (uint8_t*)d_ws;
    size_t off = 0;
    auto carve = [&](size_t bytes) -> void* {
        void* p = ws + off;
        off += (bytes + 255) & ~(size_t)255;
        return p;
    };
    uint16_t* xb  = (uint16_t*)carve((size_t)N * 128 * 2);
    uint16_t* hA  = (uint16_t*)carve((size_t)N * 64 * 2);
    uint16_t* hB  = (uint16_t*)carve((size_t)N * 64 * 2);
    uint16_t* p1  = (uint16_t*)carve((size_t)27 * 128 * 64 * 2);
    uint16_t* pt  = (uint16_t*)carve((size_t)27 * 64 * 64 * 2);
    uint16_t* p2  = (uint16_t*)carve((size_t)9 * 64 * 64 * 2);
    uint16_t* p3  = (uint16_t*)carve((size_t)9 * 64 * 64 * 2);
    uint16_t* p4  = (uint16_t*)carve((size_t)27 * 64 * 64 * 2);
    float*    bnp = (float*)carve((size_t)4 * 2 * 64 * 4);

    // prologue: convert + pack (re-done every call; ws is re-poisoned)
    const int n8 = N * 16;  // N*128/8
    convert_x<<<(n8 + 255) / 256, 256, 0, stream>>>(x, xb, n8);
    pack_weights<<<dim3(108, 6), 256, 0, stream>>>(W1, Wt, W2, W3, W4, bn,
                                                   p1, pt, p2, p3, p4, bnp);

    const int grid = (N + 63) / 64;  // 1 wave/block, 64 rows/wave
    // G=7 x 16384-row (2 MB) segments for the high-reuse CIN=64,K=27 layers.
    conv_layer<128, 27, 0, 1, 17><<<grid, 64, 0, stream>>>(xb, p1, nbr1, N, bnp + 0,   nullptr, hA, nullptr);
    conv_layer<64,  27, 1, 7, 14><<<grid, 64, 0, stream>>>(hA, pt, nbrt, N, nullptr,   skip,    hB, nullptr);
    conv_layer<64,  9,  0, 1, 17><<<grid, 64, 0, stream>>>(hB, p2, nbr2, N, bnp + 128, nullptr, hA, nullptr);
    conv_layer<64,  9,  0, 1, 17><<<grid, 64, 0, stream>>>(hA, p3, nbr3, N, bnp + 256, nullptr, hB, nullptr);
    conv_layer<64,  27, 2, 7, 14><<<grid, 64, 0, stream>>>(hB, p4, nbr4, N, bnp + 384, nullptr, nullptr, (float*)d_out);
}

// Round 5
// 1739.143 us; speedup vs baseline: 1.2754x; 1.2754x over previous
//
#include <hip/hip_runtime.h>
#include <hip/hip_cooperative_groups.h>
#include <stdint.h>

namespace cg = cooperative_groups;

// ---------------------------------------------------------------------------
// UpBlock: 5 chained sparse convs (gather-GEMM), bf16 MFMA, no LDS.
// R5: single cooperative mega-kernel (convert + pack + 5 conv phases with
// grid.sync between) to eliminate inter-dispatch idle; inner conv tile is
// EXACTLY the R1 structure (runtime K, m=64 n=64, 2x2 acc, VGPR~72) which
// runs at the measured per-CU MSHR gather ceiling (~4.4 TB/s demand).
// Fallback: if cooperative launch fails, replay the R1 multi-kernel path.
// mfma_f32_32x32x16_bf16:
//   A[m=lane&31][k=(lane>>5)*8+j], B[k=(lane>>5)*8+j][n=lane&31]
//   C/D: col=lane&31, row=(reg&3)+8*(reg>>2)+4*(lane>>5)
// ---------------------------------------------------------------------------

typedef __bf16 bf16x8 __attribute__((ext_vector_type(8)));
typedef float f32x16 __attribute__((ext_vector_type(16)));

__device__ __forceinline__ uint16_t f2bf(float f) {
    uint32_t u = __builtin_bit_cast(uint32_t, f);
    u = (u + 0x7fffu + ((u >> 16) & 1u)) >> 16;   // round-to-nearest-even
    return (uint16_t)u;
}

__device__ __forceinline__ bf16x8 ldb8(const uint16_t* p) {
    return __builtin_bit_cast(bf16x8, *reinterpret_cast<const uint4*>(p));
}

// --- work bodies (shared by fused and fallback paths) -----------------------

__device__ __forceinline__ void convert_body(const float* __restrict__ in,
                                             uint16_t* __restrict__ out, int t) {
    const float4* p = reinterpret_cast<const float4*>(in) + 2 * (size_t)t;
    float4 f0 = p[0], f1 = p[1];
    uint32_t w0 = (uint32_t)f2bf(f0.x) | ((uint32_t)f2bf(f0.y) << 16);
    uint32_t w1 = (uint32_t)f2bf(f0.z) | ((uint32_t)f2bf(f0.w) << 16);
    uint32_t w2 = (uint32_t)f2bf(f1.x) | ((uint32_t)f2bf(f1.y) << 16);
    uint32_t w3 = (uint32_t)f2bf(f1.z) | ((uint32_t)f2bf(f1.w) << 16);
    uint4 v; v.x = w0; v.y = w1; v.z = w2; v.w = w3;
    *reinterpret_cast<uint4*>(out + 8 * (size_t)t) = v;
}

// dst element [(((k*S + s)*2 + nt)*64 + l)*8 + j] = bf16(W[k][ci][c])
//   ci = s*16 + (l>>5)*8 + j,  c = nt*32 + (l&31),  S = CIN/16
__device__ __forceinline__ void pack_body(const float* __restrict__ src,
                                          uint16_t* __restrict__ dst,
                                          int CIN, int t) {
    int S = CIN / 16;
    int l = t & 63;
    int r = t >> 6;
    int nt = r & 1; r >>= 1;
    int s = r % S;
    int k = r / S;
    int c = nt * 32 + (l & 31);
    int cib = s * 16 + (l >> 5) * 8;
    #pragma unroll
    for (int j = 0; j < 8; ++j)
        dst[(size_t)t * 8 + j] = f2bf(src[((size_t)k * CIN + cib + j) * 64 + c]);
}

__device__ __forceinline__ void bn_body(const float* __restrict__ bn,
                                        float* __restrict__ bnps, int t) {
    int l = t >> 6, c = t & 63;
    float g = bn[(l * 4 + 0) * 64 + c];
    float b = bn[(l * 4 + 1) * 64 + c];
    float m = bn[(l * 4 + 2) * 64 + c];
    float v = bn[(l * 4 + 3) * 64 + c];
    float sc = g * rsqrtf(v + 1e-5f);
    bnps[(l * 2 + 0) * 64 + c] = sc;
    bnps[(l * 2 + 1) * 64 + c] = b - m * sc;
}

// One 64x64 output tile: the proven R1 inner loop (runtime K, 2x2 acc).
// MODE 0: BN+LeakyReLU -> bf16   MODE 1: +skip -> bf16   MODE 2: BN+LeakyReLU -> f32
template <int CIN, int MODE>
__device__ void conv_tile(int base, int lane,
                          const uint16_t* __restrict__ feats,
                          const uint16_t* __restrict__ wf,
                          const int* __restrict__ nbr,
                          const int K, const int npts,
                          const float* __restrict__ bnp,
                          const float* __restrict__ skip,
                          uint16_t* __restrict__ outb,
                          float* __restrict__ outf) {
    constexpr int S = CIN / 16;
    const int l31 = lane & 31;
    const int hi  = lane >> 5;
    const int r0 = base + l31;
    const int r1 = r0 + 32;
    const int g0 = min(r0, npts - 1);
    const int g1 = min(r1, npts - 1);

    f32x16 acc00 = {0,0,0,0,0,0,0,0,0,0,0,0,0,0,0,0};
    f32x16 acc01 = {0,0,0,0,0,0,0,0,0,0,0,0,0,0,0,0};
    f32x16 acc10 = {0,0,0,0,0,0,0,0,0,0,0,0,0,0,0,0};
    f32x16 acc11 = {0,0,0,0,0,0,0,0,0,0,0,0,0,0,0,0};

    for (int k = 0; k < K; ++k) {
        const int i0 = nbr[(size_t)k * npts + g0];
        const int i1 = nbr[(size_t)k * npts + g1];
        const uint16_t* a0p = feats + (size_t)i0 * CIN + hi * 8;
        const uint16_t* a1p = feats + (size_t)i1 * CIN + hi * 8;
        const uint16_t* bp  = wf + (size_t)k * (S * 1024) + lane * 8;
        #pragma unroll
        for (int s = 0; s < S; ++s) {
            bf16x8 a0 = ldb8(a0p + s * 16);
            bf16x8 a1 = ldb8(a1p + s * 16);
            bf16x8 b0 = ldb8(bp + s * 1024);
            bf16x8 b1 = ldb8(bp + s * 1024 + 512);
            acc00 = __builtin_amdgcn_mfma_f32_32x32x16_bf16(a0, b0, acc00, 0, 0, 0);
            acc01 = __builtin_amdgcn_mfma_f32_32x32x16_bf16(a0, b1, acc01, 0, 0, 0);
            acc10 = __builtin_amdgcn_mfma_f32_32x32x16_bf16(a1, b0, acc10, 0, 0, 0);
            acc11 = __builtin_amdgcn_mfma_f32_32x32x16_bf16(a1, b1, acc11, 0, 0, 0);
        }
    }

    const int c0 = l31, c1 = 32 + l31;
    float sc0 = 0.f, sh0 = 0.f, sc1 = 0.f, sh1 = 0.f;
    if (MODE != 1) {
        sc0 = bnp[c0]; sh0 = bnp[64 + c0];
        sc1 = bnp[c1]; sh1 = bnp[64 + c1];
    }
    #pragma unroll
    for (int reg = 0; reg < 16; ++reg) {
        const int row = (reg & 3) + 8 * (reg >> 2) + 4 * hi;
        const int gr0 = base + row;
        const int gr1 = base + 32 + row;
        float v00 = acc00[reg], v01 = acc01[reg];
        float v10 = acc10[reg], v11 = acc11[reg];
        if (MODE != 1) {
            v00 = v00 * sc0 + sh0; v00 = v00 >= 0.f ? v00 : 0.01f * v00;
            v01 = v01 * sc1 + sh1; v01 = v01 >= 0.f ? v01 : 0.01f * v01;
            v10 = v10 * sc0 + sh0; v10 = v10 >= 0.f ? v10 : 0.01f * v10;
            v11 = v11 * sc1 + sh1; v11 = v11 >= 0.f ? v11 : 0.01f * v11;
        }
        if (gr0 < npts) {
            if (MODE == 1) { v00 += skip[(size_t)gr0 * 64 + c0]; v01 += skip[(size_t)gr0 * 64 + c1]; }
            if (MODE == 2) {
                outf[(size_t)gr0 * 64 + c0] = v00; outf[(size_t)gr0 * 64 + c1] = v01;
            } else {
                outb[(size_t)gr0 * 64 + c0] = f2bf(v00); outb[(size_t)gr0 * 64 + c1] = f2bf(v01);
            }
        }
        if (gr1 < npts) {
            if (MODE == 1) { v10 += skip[(size_t)gr1 * 64 + c0]; v11 += skip[(size_t)gr1 * 64 + c1]; }
            if (MODE == 2) {
                outf[(size_t)gr1 * 64 + c0] = v10; outf[(size_t)gr1 * 64 + c1] = v11;
            } else {
                outb[(size_t)gr1 * 64 + c0] = f2bf(v10); outb[(size_t)gr1 * 64 + c1] = f2bf(v11);
            }
        }
    }
}

// --- params -----------------------------------------------------------------
struct UPParams {
    const float* x; const float* skip;
    const float* W1; const float* Wt; const float* W2; const float* W3; const float* W4;
    const float* bn;
    const int* nbr1; const int* nbrt; const int* nbr2; const int* nbr3; const int* nbr4;
    uint16_t* xb; uint16_t* hA; uint16_t* hB;
    uint16_t* p1; uint16_t* pt; uint16_t* p2; uint16_t* p3; uint16_t* p4;
    float* bnp; float* out;
    int N; int n8; int ntiles;
};

// --- fused cooperative kernel ------------------------------------------------
__global__ __launch_bounds__(64)
void fused_upblock(UPParams P) {
    cg::grid_group grid = cg::this_grid();
    const int lane = threadIdx.x;
    const int gthreads = gridDim.x * 64;
    const int gt0 = blockIdx.x * 64 + lane;

    // phase 0: convert x -> bf16
    for (int t = gt0; t < P.n8; t += gthreads) convert_body(P.x, P.xb, t);
    // phase 0b: pack weights + BN precompute (grid-stride per array)
    for (int t = gt0; t < 27 * 8 * 2 * 64; t += gthreads) pack_body(P.W1, P.p1, 128, t);
    for (int t = gt0; t < 27 * 4 * 2 * 64; t += gthreads) pack_body(P.Wt, P.pt, 64, t);
    for (int t = gt0; t < 9 * 4 * 2 * 64;  t += gthreads) pack_body(P.W2, P.p2, 64, t);
    for (int t = gt0; t < 9 * 4 * 2 * 64;  t += gthreads) pack_body(P.W3, P.p3, 64, t);
    for (int t = gt0; t < 27 * 4 * 2 * 64; t += gthreads) pack_body(P.W4, P.p4, 64, t);
    for (int t = gt0; t < 256; t += gthreads) bn_body(P.bn, P.bnp, t);

    __threadfence(); grid.sync(); __threadfence();

    for (int tile = blockIdx.x; tile < P.ntiles; tile += gridDim.x)
        conv_tile<128, 0>(tile * 64, lane, P.xb, P.p1, P.nbr1, 27, P.N, P.bnp, nullptr, P.hA, nullptr);
    __threadfence(); grid.sync(); __threadfence();

    for (int tile = blockIdx.x; tile < P.ntiles; tile += gridDim.x)
        conv_tile<64, 1>(tile * 64, lane, P.hA, P.pt, P.nbrt, 27, P.N, nullptr, P.skip, P.hB, nullptr);
    __threadfence(); grid.sync(); __threadfence();

    for (int tile = blockIdx.x; tile < P.ntiles; tile += gridDim.x)
        conv_tile<64, 0>(tile * 64, lane, P.hB, P.p2, P.nbr2, 9, P.N, P.bnp + 128, nullptr, P.hA, nullptr);
    __threadfence(); grid.sync(); __threadfence();

    for (int tile = blockIdx.x; tile < P.ntiles; tile += gridDim.x)
        conv_tile<64, 0>(tile * 64, lane, P.hA, P.p3, P.nbr3, 9, P.N, P.bnp + 256, nullptr, P.hB, nullptr);
    __threadfence(); grid.sync(); __threadfence();

    for (int tile = blockIdx.x; tile < P.ntiles; tile += gridDim.x)
        conv_tile<64, 2>(tile * 64, lane, P.hB, P.p4, P.nbr4, 27, P.N, P.bnp + 384, nullptr, nullptr, P.out);
}

// --- fallback standalone kernels (R1 path) -----------------------------------
__global__ void convert_x_g(const float* __restrict__ in, uint16_t* __restrict__ out, int n8) {
    int t = blockIdx.x * blockDim.x + threadIdx.x;
    if (t < n8) convert_body(in, out, t);
}

__global__ void pack_weights_g(UPParams P) {
    int w = blockIdx.y;
    int t = blockIdx.x * blockDim.x + threadIdx.x;
    switch (w) {
        case 0: if (t < 27 * 8 * 2 * 64) pack_body(P.W1, P.p1, 128, t); break;
        case 1: if (t < 27 * 4 * 2 * 64) pack_body(P.Wt, P.pt, 64, t); break;
        case 2: if (t < 9 * 4 * 2 * 64)  pack_body(P.W2, P.p2, 64, t); break;
        case 3: if (t < 9 * 4 * 2 * 64)  pack_body(P.W3, P.p3, 64, t); break;
        case 4: if (t < 27 * 4 * 2 * 64) pack_body(P.W4, P.p4, 64, t); break;
        default: if (t < 256) bn_body(P.bn, P.bnp, t); break;
    }
}

template <int CIN, int MODE>
__global__ __launch_bounds__(64)
void conv_layer_g(const uint16_t* __restrict__ feats, const uint16_t* __restrict__ wf,
                  const int* __restrict__ nbr, const int K, const int npts,
                  const float* __restrict__ bnp, const float* __restrict__ skip,
                  uint16_t* __restrict__ outb, float* __restrict__ outf) {
    conv_tile<CIN, MODE>(blockIdx.x * 64, threadIdx.x, feats, wf, nbr, K, npts, bnp, skip, outb, outf);
}

extern "C" void kernel_launch(void* const* d_in, const int* in_sizes, int n_in,
                              void* d_out, int out_size, void* d_ws, size_t ws_size,
                              hipStream_t stream) {
    const int N = in_sizes[0] / 128;

    uint8_t* ws = (uint8_t*)d_ws;
    size_t off = 0;
    auto carve = [&](size_t bytes) -> void* {
        void* p = ws + off;
        off += (bytes + 255) & ~(size_t)255;
        return p;
    };

    UPParams P;
    P.x    = (const float*)d_in[0];
    P.skip = (const float*)d_in[1];
    P.W1   = (const float*)d_in[2];
    P.Wt   = (const float*)d_in[3];
    P.W2   = (const float*)d_in[4];
    P.W3   = (const float*)d_in[5];
    P.W4   = (const float*)d_in[6];
    P.bn   = (const float*)d_in[7];
    P.nbr1 = (const int*)d_in[8];
    P.nbrt = (const int*)d_in[9];
    P.nbr2 = (const int*)d_in[10];
    P.nbr3 = (const int*)d_in[11];
    P.nbr4 = (const int*)d_in[12];
    P.xb   = (uint16_t*)carve((size_t)N * 128 * 2);
    P.hA   = (uint16_t*)carve((size_t)N * 64 * 2);
    P.hB   = (uint16_t*)carve((size_t)N * 64 * 2);
    P.p1   = (uint16_t*)carve((size_t)27 * 128 * 64 * 2);
    P.pt   = (uint16_t*)carve((size_t)27 * 64 * 64 * 2);
    P.p2   = (uint16_t*)carve((size_t)9 * 64 * 64 * 2);
    P.p3   = (uint16_t*)carve((size_t)9 * 64 * 64 * 2);
    P.p4   = (uint16_t*)carve((size_t)27 * 64 * 64 * 2);
    P.bnp  = (float*)carve((size_t)4 * 2 * 64 * 4);
    P.out  = (float*)d_out;
    P.N = N;
    P.n8 = N * 16;
    P.ntiles = (N + 63) / 64;

    // Try the fused cooperative kernel; on any launch error fall back to the
    // proven R1 multi-kernel path (both compute identical results).
    void* kargs[] = { (void*)&P };
    hipError_t err = hipLaunchCooperativeKernel((const void*)fused_upblock,
                                                dim3(P.ntiles), dim3(64),
                                                kargs, 0, stream);
    if (err != hipSuccess) {
        convert_x_g<<<(P.n8 + 255) / 256, 256, 0, stream>>>(P.x, P.xb, P.n8);
        pack_weights_g<<<dim3(108, 6), 256, 0, stream>>>(P);
        const int grid = P.ntiles;
        conv_layer_g<128, 0><<<grid, 64, 0, stream>>>(P.xb, P.p1, P.nbr1, 27, N, P.bnp,       nullptr, P.hA, nullptr);
        conv_layer_g<64,  1><<<grid, 64, 0, stream>>>(P.hA, P.pt, P.nbrt, 27, N, nullptr,     P.skip,  P.hB, nullptr);
        conv_layer_g<64,  0><<<grid, 64, 0, stream>>>(P.hB, P.p2, P.nbr2, 9,  N, P.bnp + 128, nullptr, P.hA, nullptr);
        conv_layer_g<64,  0><<<grid, 64, 0, stream>>>(P.hA, P.p3, P.nbr3, 9,  N, P.bnp + 256, nullptr, P.hB, nullptr);
        conv_layer_g<64,  2><<<grid, 64, 0, stream>>>(P.hB, P.p4, P.nbr4, 27, N, P.bnp + 384, nullptr, nullptr, P.out);
    }
}

// Round 6
// 548.349 us; speedup vs baseline: 4.0452x; 3.1716x over previous
//
#include <hip/hip_runtime.h>
#include <stdint.h>

// ---------------------------------------------------------------------------
// UpBlock: 5 chained sparse convs (gather-GEMM), bf16 MFMA.
// R6: R1 per-wave tile (m=64 n=64, 2x2 acc, direct A-gathers from L2/L3),
// but 4 waves/block SHARE the B fragments via LDS: B staged in 64 KB chunks
// (C taps at a time), consumed by all 4 waves -> 4x less redundant B traffic
// on the L1<->L2 path, which R1/R2 evidence implicates as the contended
// resource (time ~ K, not A-bytes; 2x waves -> worse).
// mfma_f32_32x32x16_bf16:
//   A[m=lane&31][k=(lane>>5)*8+j], B[k=(lane>>5)*8+j][n=lane&31]
//   C/D: col=lane&31, row=(reg&3)+8*(reg>>2)+4*(lane>>5)
// ---------------------------------------------------------------------------

typedef __bf16 bf16x8 __attribute__((ext_vector_type(8)));
typedef float f32x16 __attribute__((ext_vector_type(16)));

__device__ __forceinline__ uint16_t f2bf(float f) {
    uint32_t u = __builtin_bit_cast(uint32_t, f);
    u = (u + 0x7fffu + ((u >> 16) & 1u)) >> 16;   // round-to-nearest-even
    return (uint16_t)u;
}

__device__ __forceinline__ bf16x8 ldb8(const uint16_t* p) {
    return __builtin_bit_cast(bf16x8, *reinterpret_cast<const uint4*>(p));
}

// --- convert x_feats (f32) -> bf16, 8 elems/thread --------------------------
__global__ void convert_x(const float* __restrict__ in, uint16_t* __restrict__ out, int n8) {
    int t = blockIdx.x * blockDim.x + threadIdx.x;
    if (t >= n8) return;
    const float4* p = reinterpret_cast<const float4*>(in) + 2 * (size_t)t;
    float4 f0 = p[0], f1 = p[1];
    uint32_t w0 = (uint32_t)f2bf(f0.x) | ((uint32_t)f2bf(f0.y) << 16);
    uint32_t w1 = (uint32_t)f2bf(f0.z) | ((uint32_t)f2bf(f0.w) << 16);
    uint32_t w2 = (uint32_t)f2bf(f1.x) | ((uint32_t)f2bf(f1.y) << 16);
    uint32_t w3 = (uint32_t)f2bf(f1.z) | ((uint32_t)f2bf(f1.w) << 16);
    uint4 v; v.x = w0; v.y = w1; v.z = w2; v.w = w3;
    *reinterpret_cast<uint4*>(out + 8 * (size_t)t) = v;
}

// --- pack weights into MFMA B-fragment order + BN scale/shift ---------------
// dst element [(((k*S + s)*2 + nt)*64 + lane)*8 + j] = bf16(W[k][ci][c])
//   ci = s*16 + (lane>>5)*8 + j,  c = nt*32 + (lane&31),  S = CIN/16
__global__ void pack_weights(const float* __restrict__ w1, const float* __restrict__ wt,
                             const float* __restrict__ w2, const float* __restrict__ w3,
                             const float* __restrict__ w4, const float* __restrict__ bn,
                             uint16_t* __restrict__ p1, uint16_t* __restrict__ pt,
                             uint16_t* __restrict__ p2, uint16_t* __restrict__ p3,
                             uint16_t* __restrict__ p4, float* __restrict__ bnps) {
    int w = blockIdx.y;
    int t = blockIdx.x * blockDim.x + threadIdx.x;
    if (w == 5) {  // BN scale/shift precompute: bnps[l][0][c]=scale, [l][1][c]=shift
        if (t < 256) {
            int l = t >> 6, c = t & 63;
            float g = bn[(l * 4 + 0) * 64 + c];
            float b = bn[(l * 4 + 1) * 64 + c];
            float m = bn[(l * 4 + 2) * 64 + c];
            float v = bn[(l * 4 + 3) * 64 + c];
            float sc = g * rsqrtf(v + 1e-5f);
            bnps[(l * 2 + 0) * 64 + c] = sc;
            bnps[(l * 2 + 1) * 64 + c] = b - m * sc;
        }
        return;
    }
    const float* src; uint16_t* dst; int K, CIN;
    switch (w) {
        case 0:  src = w1; dst = p1; K = 27; CIN = 128; break;
        case 1:  src = wt; dst = pt; K = 27; CIN = 64;  break;
        case 2:  src = w2; dst = p2; K = 9;  CIN = 64;  break;
        case 3:  src = w3; dst = p3; K = 9;  CIN = 64;  break;
        default: src = w4; dst = p4; K = 27; CIN = 64;  break;
    }
    int S = CIN / 16;
    int F = K * S * 2 * 64;
    if (t >= F) return;
    int lane = t & 63;
    int r = t >> 6;
    int nt = r & 1; r >>= 1;
    int s = r % S;
    int k = r / S;
    int c = nt * 32 + (lane & 31);
    int cib = s * 16 + (lane >> 5) * 8;
    #pragma unroll
    for (int j = 0; j < 8; ++j)
        dst[(size_t)t * 8 + j] = f2bf(src[((size_t)k * CIN + cib + j) * 64 + c]);
}

// --- one sparse-conv layer ---------------------------------------------------
// 4 waves/block; wave w owns m-tile (blockIdx*4+w)*64; all share LDS-staged B.
// MODE 0: BN+LeakyReLU -> bf16   MODE 1: +skip -> bf16   MODE 2: BN+LeakyReLU -> f32
template <int CIN, int K, int MODE>
__global__ __launch_bounds__(256)
void conv_layer(const uint16_t* __restrict__ feats,  // [N][CIN] bf16
                const uint16_t* __restrict__ wf,     // packed [K][CIN/16][2][64][8] bf16
                const int* __restrict__ nbr,         // [K][N]
                const int npts,
                const float* __restrict__ bnp,       // [2][64] scale/shift (or null)
                const float* __restrict__ skip,      // [N][64] f32 (or null)
                uint16_t* __restrict__ outb,
                float* __restrict__ outf) {
    constexpr int S = CIN / 16;          // 16-wide K-slices per tap
    constexpr int C = 32 / S;            // taps per 64 KB LDS chunk (4 or 8)
    constexpr int NFULL = K / C;
    constexpr int REM = K % C;

    __shared__ uint16_t Bs[32768];       // 64 KB: C * S * 2 * 512 elems

    const int lane = threadIdx.x & 63;
    const int wave = threadIdx.x >> 6;
    const int l31  = lane & 31;
    const int hi   = lane >> 5;          // which K-half of the fragment
    const int base = (blockIdx.x * 4 + wave) * 64;
    const int g0   = min(base + l31, npts - 1);
    const int g1   = min(base + 32 + l31, npts - 1);

    f32x16 acc00 = {0,0,0,0,0,0,0,0,0,0,0,0,0,0,0,0};
    f32x16 acc01 = {0,0,0,0,0,0,0,0,0,0,0,0,0,0,0,0};
    f32x16 acc10 = {0,0,0,0,0,0,0,0,0,0,0,0,0,0,0,0};
    f32x16 acc11 = {0,0,0,0,0,0,0,0,0,0,0,0,0,0,0,0};

    auto stage = [&](int k0, int units) {   // units of 16 B
        const uint4* gsrc = reinterpret_cast<const uint4*>(wf + (size_t)k0 * (S * 1024));
        uint4* dst = reinterpret_cast<uint4*>(Bs);
        for (int u = threadIdx.x; u < units; u += 256) dst[u] = gsrc[u];
    };

    auto do_tap = [&](int k, int kk) {      // k: global tap, kk: tap within chunk
        const int i0 = nbr[(size_t)k * npts + g0];
        const int i1 = nbr[(size_t)k * npts + g1];
        const uint16_t* a0p = feats + (size_t)i0 * CIN + hi * 8;
        const uint16_t* a1p = feats + (size_t)i1 * CIN + hi * 8;
        #pragma unroll
        for (int s = 0; s < S; ++s) {
            bf16x8 a0 = ldb8(a0p + s * 16);
            bf16x8 a1 = ldb8(a1p + s * 16);
            const uint16_t* bp = Bs + ((kk * S + s) * 2) * 512 + lane * 8;
            bf16x8 b0 = ldb8(bp);
            bf16x8 b1 = ldb8(bp + 512);
            acc00 = __builtin_amdgcn_mfma_f32_32x32x16_bf16(a0, b0, acc00, 0, 0, 0);
            acc01 = __builtin_amdgcn_mfma_f32_32x32x16_bf16(a0, b1, acc01, 0, 0, 0);
            acc10 = __builtin_amdgcn_mfma_f32_32x32x16_bf16(a1, b0, acc10, 0, 0, 0);
            acc11 = __builtin_amdgcn_mfma_f32_32x32x16_bf16(a1, b1, acc11, 0, 0, 0);
        }
    };

    for (int c = 0; c < NFULL; ++c) {
        stage(c * C, C * S * 128);
        __syncthreads();
        #pragma unroll
        for (int kk = 0; kk < C; ++kk) do_tap(c * C + kk, kk);
        __syncthreads();
    }
    if constexpr (REM > 0) {
        stage(NFULL * C, REM * S * 128);
        __syncthreads();
        #pragma unroll
        for (int kk = 0; kk < REM; ++kk) do_tap(NFULL * C + kk, kk);
        __syncthreads();
    }

    const int c0 = l31, c1 = 32 + l31;
    float sc0 = 0.f, sh0 = 0.f, sc1 = 0.f, sh1 = 0.f;
    if (MODE != 1) {
        sc0 = bnp[c0]; sh0 = bnp[64 + c0];
        sc1 = bnp[c1]; sh1 = bnp[64 + c1];
    }
    #pragma unroll
    for (int reg = 0; reg < 16; ++reg) {
        const int row = (reg & 3) + 8 * (reg >> 2) + 4 * hi;
        const int gr0 = base + row;
        const int gr1 = base + 32 + row;
        float v00 = acc00[reg], v01 = acc01[reg];
        float v10 = acc10[reg], v11 = acc11[reg];
        if (MODE != 1) {
            v00 = v00 * sc0 + sh0; v00 = v00 >= 0.f ? v00 : 0.01f * v00;
            v01 = v01 * sc1 + sh1; v01 = v01 >= 0.f ? v01 : 0.01f * v01;
            v10 = v10 * sc0 + sh0; v10 = v10 >= 0.f ? v10 : 0.01f * v10;
            v11 = v11 * sc1 + sh1; v11 = v11 >= 0.f ? v11 : 0.01f * v11;
        }
        if (gr0 < npts) {
            if (MODE == 1) { v00 += skip[(size_t)gr0 * 64 + c0]; v01 += skip[(size_t)gr0 * 64 + c1]; }
            if (MODE == 2) {
                outf[(size_t)gr0 * 64 + c0] = v00; outf[(size_t)gr0 * 64 + c1] = v01;
            } else {
                outb[(size_t)gr0 * 64 + c0] = f2bf(v00); outb[(size_t)gr0 * 64 + c1] = f2bf(v01);
            }
        }
        if (gr1 < npts) {
            if (MODE == 1) { v10 += skip[(size_t)gr1 * 64 + c0]; v11 += skip[(size_t)gr1 * 64 + c1]; }
            if (MODE == 2) {
                outf[(size_t)gr1 * 64 + c0] = v10; outf[(size_t)gr1 * 64 + c1] = v11;
            } else {
                outb[(size_t)gr1 * 64 + c0] = f2bf(v10); outb[(size_t)gr1 * 64 + c1] = f2bf(v11);
            }
        }
    }
}

extern "C" void kernel_launch(void* const* d_in, const int* in_sizes, int n_in,
                              void* d_out, int out_size, void* d_ws, size_t ws_size,
                              hipStream_t stream) {
    const int N = in_sizes[0] / 128;
    const float* x    = (const float*)d_in[0];
    const float* skip = (const float*)d_in[1];
    const float* W1   = (const float*)d_in[2];
    const float* Wt   = (const float*)d_in[3];
    const float* W2   = (const float*)d_in[4];
    const float* W3   = (const float*)d_in[5];
    const float* W4   = (const float*)d_in[6];
    const float* bn   = (const float*)d_in[7];
    const int* nbr1   = (const int*)d_in[8];
    const int* nbrt   = (const int*)d_in[9];
    const int* nbr2   = (const int*)d_in[10];
    const int* nbr3   = (const int*)d_in[11];
    const int* nbr4   = (const int*)d_in[12];

    uint8_t* ws = (uint8_t*)d_ws;
    size_t off = 0;
    auto carve = [&](size_t bytes) -> void* {
        void* p = ws + off;
        off += (bytes + 255) & ~(size_t)255;
        return p;
    };
    uint16_t* xb  = (uint16_t*)carve((size_t)N * 128 * 2);
    uint16_t* hA  = (uint16_t*)carve((size_t)N * 64 * 2);
    uint16_t* hB  = (uint16_t*)carve((size_t)N * 64 * 2);
    uint16_t* p1  = (uint16_t*)carve((size_t)27 * 128 * 64 * 2);
    uint16_t* pt  = (uint16_t*)carve((size_t)27 * 64 * 64 * 2);
    uint16_t* p2  = (uint16_t*)carve((size_t)9 * 64 * 64 * 2);
    uint16_t* p3  = (uint16_t*)carve((size_t)9 * 64 * 64 * 2);
    uint16_t* p4  = (uint16_t*)carve((size_t)27 * 64 * 64 * 2);
    float*    bnp = (float*)carve((size_t)4 * 2 * 64 * 4);

    // prologue: convert + pack (re-done every call; ws is re-poisoned)
    const int n8 = N * 16;  // N*128/8
    convert_x<<<(n8 + 255) / 256, 256, 0, stream>>>(x, xb, n8);
    pack_weights<<<dim3(108, 6), 256, 0, stream>>>(W1, Wt, W2, W3, W4, bn,
                                                   p1, pt, p2, p3, p4, bnp);

    const int grid = (N + 255) / 256;  // 4 waves/block, 64 rows/wave
    conv_layer<128, 27, 0><<<grid, 256, 0, stream>>>(xb, p1, nbr1, N, bnp + 0,   nullptr, hA, nullptr);
    conv_layer<64,  27, 1><<<grid, 256, 0, stream>>>(hA, pt, nbrt, N, nullptr,   skip,    hB, nullptr);
    conv_layer<64,  9,  0><<<grid, 256, 0, stream>>>(hB, p2, nbr2, N, bnp + 128, nullptr, hA, nullptr);
    conv_layer<64,  9,  0><<<grid, 256, 0, stream>>>(hA, p3, nbr3, N, bnp + 256, nullptr, hB, nullptr);
    conv_layer<64,  27, 2><<<grid, 256, 0, stream>>>(hB, p4, nbr4, N, bnp + 384, nullptr, nullptr, (float*)d_out);
}